// Round 1
// baseline (432.523 us; speedup 1.0000x reference)
//
#include <hip/hip_runtime.h>
#include <math.h>

#define N 4
#define V 5
#define C 128
#define H 128
#define W 128
#define P 4096

// d_out layout (flat concat, all float32):
//   feats      : N*P*V*C = 10485760
//   bounding   : N*P     = 16384      (bool -> 1.0f/0.0f)
//   sample_pts : N*P*5   = 81920
__global__ __launch_bounds__(128) void project_sample_kernel(
    const float* __restrict__ fm,      // (N,V,C,H,W)
    const float* __restrict__ sp,      // (N,P,5)
    const float* __restrict__ Rm,      // (N,V,3,3)
    const float* __restrict__ Tm,      // (N,V,3)
    const float* __restrict__ fv,      // (N,V,2)
    const float* __restrict__ cv,      // (N,V,2)
    const float* __restrict__ kv,      // (N,V,3)
    const float* __restrict__ pv,      // (N,V,2)
    const float* __restrict__ trans,   // (N,V,2,3)
    const float* __restrict__ wh,      // (N,V,2)
    const float* __restrict__ fmsz,    // (2,)
    float* __restrict__ out_feats,     // (N,P,V,C)
    float* __restrict__ out_bound,     // (N,P)
    float* __restrict__ out_sp)        // (N,P,5)
{
    const int blk = blockIdx.x;            // n*P + p
    const int n   = blk / P;
    const int tid = threadIdx.x;           // channel 0..127

    // passthrough copy of sample_points
    if (tid < 5) out_sp[blk * 5 + tid] = sp[blk * 5 + tid];

    const float X = sp[blk * 5 + 0];
    const float Y = sp[blk * 5 + 1];
    const float Z = sp[blk * 5 + 2];

    __shared__ int s_nan;
    if (tid == 0) s_nan = 0;
    __syncthreads();

    const float fm0 = fmsz[0], fm1 = fmsz[1];

    bool any_bound = false;
    bool any_nan   = false;

    for (int v = 0; v < V; ++v) {
        const int nv = n * V + v;
        const float* Rv = Rm + nv * 9;
        const float tx = Tm[nv * 3 + 0], ty = Tm[nv * 3 + 1], tz = Tm[nv * 3 + 2];
        const float px = X - tx, py = Y - ty, pz = Z - tz;
        const float Xc0 = Rv[0] * px + Rv[1] * py + Rv[2] * pz;
        const float Xc1 = Rv[3] * px + Rv[4] * py + Rv[5] * pz;
        const float Xc2 = Rv[6] * px + Rv[7] * py + Rv[8] * pz;
        const float xn = Xc0 / Xc2;
        const float yn = Xc1 / Xc2;
        const float r2 = xn * xn + yn * yn;
        const float k1 = kv[nv * 3 + 0], k2 = kv[nv * 3 + 1], k3 = kv[nv * 3 + 2];
        const float p1 = pv[nv * 2 + 0], p2 = pv[nv * 2 + 1];
        const float radial = 1.0f + k1 * r2 + k2 * r2 * r2 + k3 * r2 * r2 * r2;
        const float xd = xn * radial + 2.0f * p1 * xn * yn + p2 * (r2 + 2.0f * xn * xn);
        const float yd = yn * radial + p1 * (r2 + 2.0f * yn * yn) + 2.0f * p2 * xn * yn;
        const float xy0 = xd * fv[nv * 2 + 0] + cv[nv * 2 + 0];
        const float xy1 = yd * fv[nv * 2 + 1] + cv[nv * 2 + 1];
        const float width  = wh[nv * 2 + 0];
        const float height = wh[nv * 2 + 1];
        const bool bound = (xy0 >= 0.0f) && (xy1 >= 0.0f) && (xy0 < width) && (xy1 < height);
        const float maxwh = fmaxf(width, height);
        const float pix0 = fminf(fmaxf(xy0, -1.0f), maxwh);
        const float pix1 = fminf(fmaxf(xy1, -1.0f), maxwh);
        const float* tr = trans + nv * 6;
        const float pt0 = tr[0] * pix0 + tr[1] * pix1 + tr[2];
        const float pt1 = tr[3] * pix0 + tr[4] * pix1 + tr[5];
        float g0 = pt0 / (fm0 - 1.0f) * 2.0f - 1.0f;
        float g1 = pt1 / (fm1 - 1.0f) * 2.0f - 1.0f;
        g0 = fminf(fmaxf(g0, -1.1f), 1.1f);
        g1 = fminf(fmaxf(g1, -1.1f), 1.1f);

        // bilinear grid sample, zero padding outside
        const float xg = (g0 + 1.0f) * 0.5f * (float)(W - 1);
        const float yg = (g1 + 1.0f) * 0.5f * (float)(H - 1);
        const float x0f = floorf(xg), y0f = floorf(yg);
        const float wx1 = xg - x0f, wx0 = 1.0f - wx1;
        const float wy1 = yg - y0f, wy0 = 1.0f - wy1;
        const int x0 = (int)x0f, y0 = (int)y0f;
        const int x1 = x0 + 1,  y1 = y0 + 1;
        const bool vx0 = (x0 >= 0) && (x0 <= W - 1);
        const bool vx1 = (x1 >= 0) && (x1 <= W - 1);
        const bool vy0 = (y0 >= 0) && (y0 <= H - 1);
        const bool vy1 = (y1 >= 0) && (y1 <= H - 1);
        const int x0c = min(max(x0, 0), W - 1);
        const int x1c = min(max(x1, 0), W - 1);
        const int y0c = min(max(y0, 0), H - 1);
        const int y1c = min(max(y1, 0), H - 1);

        const float* img = fm + ((size_t)nv * C + tid) * (size_t)(H * W);
        const float v00 = (vx0 && vy0) ? img[y0c * W + x0c] : 0.0f;
        const float v10 = (vx1 && vy0) ? img[y0c * W + x1c] : 0.0f;
        const float v01 = (vx0 && vy1) ? img[y1c * W + x0c] : 0.0f;
        const float v11 = (vx1 && vy1) ? img[y1c * W + x1c] : 0.0f;

        const float s = v00 * (wx0 * wy0) + v10 * (wx1 * wy0)
                      + v01 * (wx0 * wy1) + v11 * (wx1 * wy1);
        const float feat = s * (bound ? 1.0f : 0.0f);

        any_nan  |= (feat != feat);
        any_bound |= bound;
        out_feats[((size_t)blk * V + v) * C + tid] = feat;
    }

    if (any_nan) s_nan = 1;   // benign race: all writers store 1
    __syncthreads();
    if (tid == 0) {
        out_bound[blk] = (any_bound && (s_nan == 0)) ? 1.0f : 0.0f;
    }
}

extern "C" void kernel_launch(void* const* d_in, const int* in_sizes, int n_in,
                              void* d_out, int out_size, void* d_ws, size_t ws_size,
                              hipStream_t stream) {
    const float* fm    = (const float*)d_in[0];
    const float* sp    = (const float*)d_in[1];
    const float* Rm    = (const float*)d_in[2];
    const float* Tm    = (const float*)d_in[3];
    const float* fv    = (const float*)d_in[4];
    const float* cv    = (const float*)d_in[5];
    const float* kv    = (const float*)d_in[6];
    const float* pv    = (const float*)d_in[7];
    const float* trans = (const float*)d_in[8];
    const float* wh    = (const float*)d_in[9];
    const float* fmsz  = (const float*)d_in[10];

    float* out        = (float*)d_out;
    float* out_feats  = out;
    float* out_bound  = out + (size_t)N * P * V * C;
    float* out_sp     = out_bound + (size_t)N * P;

    project_sample_kernel<<<N * P, 128, 0, stream>>>(
        fm, sp, Rm, Tm, fv, cv, kv, pv, trans, wh, fmsz,
        out_feats, out_bound, out_sp);
}

// Round 2
// 327.523 us; speedup vs baseline: 1.3206x; 1.3206x over previous
//
#include <hip/hip_runtime.h>
#include <math.h>

#define N 4
#define V 5
#define C 128
#define H 128
#define W 128
#define P 4096
#define HW (H * W)

// ---------------------------------------------------------------------------
// Transpose (N,V,C,H,W) -> (N,V,H,W,C)  [channel-last] into workspace.
// One block per (nv, 64-wide hw tile). 256 threads.
// ---------------------------------------------------------------------------
__global__ __launch_bounds__(256) void transpose_kernel(
    const float* __restrict__ fm, float* __restrict__ fmT)
{
    const int nv  = blockIdx.y;          // 0..N*V-1
    const int hw0 = blockIdx.x * 64;     // tile start in hw
    __shared__ float lds[64 * 129];      // [hw_local][c], pad 129 to break stride

    const int t    = threadIdx.x;
    const int hw_l = t & 63;             // 0..63
    const int c0   = t >> 6;             // 0..3

    const float* src = fm + (size_t)nv * C * HW + hw0;
    for (int c = c0; c < C; c += 4) {
        lds[hw_l * 129 + c] = src[(size_t)c * HW + hw_l];
    }
    __syncthreads();

    const int c     = t & 127;           // 0..127
    const int hwl0  = t >> 7;            // 0..1
    float* dst = fmT + ((size_t)nv * HW + hw0) * C;
    for (int hw = hwl0; hw < 64; hw += 2) {
        dst[(size_t)hw * C + c] = lds[hw * 129 + c];
    }
}

// ---------------------------------------------------------------------------
// Projection + bilinear sample from channel-last maps.
// One block per (n,p); 128 threads = channels. Each corner read is a
// contiguous 512 B burst across the block (fully coalesced).
// ---------------------------------------------------------------------------
template <bool CHANNEL_LAST>
__global__ __launch_bounds__(128) void project_sample_kernel(
    const float* __restrict__ fm,      // CHANNEL_LAST ? (N,V,H,W,C) : (N,V,C,H,W)
    const float* __restrict__ sp,      // (N,P,5)
    const float* __restrict__ Rm,      // (N,V,3,3)
    const float* __restrict__ Tm,      // (N,V,3)
    const float* __restrict__ fv,      // (N,V,2)
    const float* __restrict__ cv,      // (N,V,2)
    const float* __restrict__ kv,      // (N,V,3)
    const float* __restrict__ pv,      // (N,V,2)
    const float* __restrict__ trans,   // (N,V,2,3)
    const float* __restrict__ wh,      // (N,V,2)
    const float* __restrict__ fmsz,    // (2,)
    float* __restrict__ out_feats,     // (N,P,V,C)
    float* __restrict__ out_bound,     // (N,P)
    float* __restrict__ out_sp)        // (N,P,5)
{
    const int blk = blockIdx.x;            // n*P + p
    const int n   = blk / P;
    const int tid = threadIdx.x;           // channel 0..127

    if (tid < 5) out_sp[blk * 5 + tid] = sp[blk * 5 + tid];

    const float X = sp[blk * 5 + 0];
    const float Y = sp[blk * 5 + 1];
    const float Z = sp[blk * 5 + 2];

    __shared__ int s_nan;
    if (tid == 0) s_nan = 0;
    __syncthreads();

    const float fm0 = fmsz[0], fm1 = fmsz[1];

    bool any_bound = false;
    bool any_nan   = false;

    for (int v = 0; v < V; ++v) {
        const int nv = n * V + v;
        const float* Rv = Rm + nv * 9;
        const float tx = Tm[nv * 3 + 0], ty = Tm[nv * 3 + 1], tz = Tm[nv * 3 + 2];
        const float px = X - tx, py = Y - ty, pz = Z - tz;
        const float Xc0 = Rv[0] * px + Rv[1] * py + Rv[2] * pz;
        const float Xc1 = Rv[3] * px + Rv[4] * py + Rv[5] * pz;
        const float Xc2 = Rv[6] * px + Rv[7] * py + Rv[8] * pz;
        const float xn = Xc0 / Xc2;
        const float yn = Xc1 / Xc2;
        const float r2 = xn * xn + yn * yn;
        const float k1 = kv[nv * 3 + 0], k2 = kv[nv * 3 + 1], k3 = kv[nv * 3 + 2];
        const float p1 = pv[nv * 2 + 0], p2 = pv[nv * 2 + 1];
        const float radial = 1.0f + k1 * r2 + k2 * r2 * r2 + k3 * r2 * r2 * r2;
        const float xd = xn * radial + 2.0f * p1 * xn * yn + p2 * (r2 + 2.0f * xn * xn);
        const float yd = yn * radial + p1 * (r2 + 2.0f * yn * yn) + 2.0f * p2 * xn * yn;
        const float xy0 = xd * fv[nv * 2 + 0] + cv[nv * 2 + 0];
        const float xy1 = yd * fv[nv * 2 + 1] + cv[nv * 2 + 1];
        const float width  = wh[nv * 2 + 0];
        const float height = wh[nv * 2 + 1];
        const bool bound = (xy0 >= 0.0f) && (xy1 >= 0.0f) && (xy0 < width) && (xy1 < height);
        const float maxwh = fmaxf(width, height);
        const float pix0 = fminf(fmaxf(xy0, -1.0f), maxwh);
        const float pix1 = fminf(fmaxf(xy1, -1.0f), maxwh);
        const float* tr = trans + nv * 6;
        const float pt0 = tr[0] * pix0 + tr[1] * pix1 + tr[2];
        const float pt1 = tr[3] * pix0 + tr[4] * pix1 + tr[5];
        float g0 = pt0 / (fm0 - 1.0f) * 2.0f - 1.0f;
        float g1 = pt1 / (fm1 - 1.0f) * 2.0f - 1.0f;
        g0 = fminf(fmaxf(g0, -1.1f), 1.1f);
        g1 = fminf(fmaxf(g1, -1.1f), 1.1f);

        const float xg = (g0 + 1.0f) * 0.5f * (float)(W - 1);
        const float yg = (g1 + 1.0f) * 0.5f * (float)(H - 1);
        const float x0f = floorf(xg), y0f = floorf(yg);
        const float wx1 = xg - x0f, wx0 = 1.0f - wx1;
        const float wy1 = yg - y0f, wy0 = 1.0f - wy1;
        const int x0 = (int)x0f, y0 = (int)y0f;
        const int x1 = x0 + 1,  y1 = y0 + 1;
        const bool vx0 = (x0 >= 0) && (x0 <= W - 1);
        const bool vx1 = (x1 >= 0) && (x1 <= W - 1);
        const bool vy0 = (y0 >= 0) && (y0 <= H - 1);
        const bool vy1 = (y1 >= 0) && (y1 <= H - 1);
        const int x0c = min(max(x0, 0), W - 1);
        const int x1c = min(max(x1, 0), W - 1);
        const int y0c = min(max(y0, 0), H - 1);
        const int y1c = min(max(y1, 0), H - 1);

        float v00, v10, v01, v11;
        if (CHANNEL_LAST) {
            const float* img = fm + (size_t)nv * HW * C;
            v00 = (vx0 && vy0) ? img[((size_t)(y0c * W + x0c)) * C + tid] : 0.0f;
            v10 = (vx1 && vy0) ? img[((size_t)(y0c * W + x1c)) * C + tid] : 0.0f;
            v01 = (vx0 && vy1) ? img[((size_t)(y1c * W + x0c)) * C + tid] : 0.0f;
            v11 = (vx1 && vy1) ? img[((size_t)(y1c * W + x1c)) * C + tid] : 0.0f;
        } else {
            const float* img = fm + ((size_t)nv * C + tid) * (size_t)HW;
            v00 = (vx0 && vy0) ? img[y0c * W + x0c] : 0.0f;
            v10 = (vx1 && vy0) ? img[y0c * W + x1c] : 0.0f;
            v01 = (vx0 && vy1) ? img[y1c * W + x0c] : 0.0f;
            v11 = (vx1 && vy1) ? img[y1c * W + x1c] : 0.0f;
        }

        const float s = v00 * (wx0 * wy0) + v10 * (wx1 * wy0)
                      + v01 * (wx0 * wy1) + v11 * (wx1 * wy1);
        const float feat = s * (bound ? 1.0f : 0.0f);

        any_nan   |= (feat != feat);
        any_bound |= bound;
        out_feats[((size_t)blk * V + v) * C + tid] = feat;
    }

    if (any_nan) s_nan = 1;
    __syncthreads();
    if (tid == 0) {
        out_bound[blk] = (any_bound && (s_nan == 0)) ? 1.0f : 0.0f;
    }
}

extern "C" void kernel_launch(void* const* d_in, const int* in_sizes, int n_in,
                              void* d_out, int out_size, void* d_ws, size_t ws_size,
                              hipStream_t stream) {
    const float* fm    = (const float*)d_in[0];
    const float* sp    = (const float*)d_in[1];
    const float* Rm    = (const float*)d_in[2];
    const float* Tm    = (const float*)d_in[3];
    const float* fv    = (const float*)d_in[4];
    const float* cv    = (const float*)d_in[5];
    const float* kv    = (const float*)d_in[6];
    const float* pv    = (const float*)d_in[7];
    const float* trans = (const float*)d_in[8];
    const float* wh    = (const float*)d_in[9];
    const float* fmsz  = (const float*)d_in[10];

    float* out        = (float*)d_out;
    float* out_feats  = out;
    float* out_bound  = out + (size_t)N * P * V * C;
    float* out_sp     = out_bound + (size_t)N * P;

    const size_t fmT_bytes = (size_t)N * V * C * HW * sizeof(float);

    if (ws_size >= fmT_bytes) {
        float* fmT = (float*)d_ws;
        dim3 tgrid(HW / 64, N * V);
        transpose_kernel<<<tgrid, 256, 0, stream>>>(fm, fmT);
        project_sample_kernel<true><<<N * P, 128, 0, stream>>>(
            fmT, sp, Rm, Tm, fv, cv, kv, pv, trans, wh, fmsz,
            out_feats, out_bound, out_sp);
    } else {
        project_sample_kernel<false><<<N * P, 128, 0, stream>>>(
            fm, sp, Rm, Tm, fv, cv, kv, pv, trans, wh, fmsz,
            out_feats, out_bound, out_sp);
    }
}

// Round 4
// 301.424 us; speedup vs baseline: 1.4349x; 1.0866x over previous
//
#include <hip/hip_runtime.h>
#include <math.h>

#define N 4
#define V 5
#define C 128
#define H 128
#define W 128
#define P 4096
#define HW (H * W)
#define PTS 16              // points per project block

typedef float fvec4 __attribute__((ext_vector_type(4)));

// ---------------------------------------------------------------------------
// Transpose (N,V,C,H,W) -> (N,V,H,W,C), float4 both sides.
// Tile: 64 hw x 128 c. 256 threads.
// ---------------------------------------------------------------------------
__global__ __launch_bounds__(256) void transpose_kernel(
    const float* __restrict__ fm, float* __restrict__ fmT)
{
    const int nv  = blockIdx.y;          // 0..N*V-1
    const int hw0 = blockIdx.x * 64;     // tile start in hw
    __shared__ float lds[64][C + 1];     // +1 pad breaks power-of-2 stride

    const int t = threadIdx.x;

    // Load: thread covers 4 consecutive hw at one c; 16 c per pass, 8 passes.
    {
        const int hwl = (t & 15) * 4;
        const int cb  = t >> 4;          // 0..15
        const float* src = fm + (size_t)nv * C * HW + hw0 + hwl;
        for (int c = cb; c < C; c += 16) {
            const fvec4 v = __builtin_nontemporal_load(
                (const fvec4*)(src + (size_t)c * HW));
            lds[hwl + 0][c] = v.x;
            lds[hwl + 1][c] = v.y;
            lds[hwl + 2][c] = v.z;
            lds[hwl + 3][c] = v.w;
        }
    }
    __syncthreads();

    // Store: thread covers 4 consecutive c at one hw; 8 hw per pass, 8 passes.
    {
        const int c4 = (t & 31) * 4;
        float* dst = fmT + ((size_t)nv * HW + hw0) * C + c4;
        for (int hw = (t >> 5); hw < 64; hw += 8) {
            const fvec4 v = *(const fvec4*)&lds[hw][c4];
            *(fvec4*)(dst + (size_t)hw * C) = v;
        }
    }
}

// ---------------------------------------------------------------------------
// Phase-split projection + gather. Block = 256 threads, PTS points.
// Phase 1: 80 threads compute one (pt,view) projection each -> LDS.
// Phase 2: two 128-lane groups stream the coalesced channel gathers.
// ---------------------------------------------------------------------------
__global__ __launch_bounds__(256) void project_sample_kernel(
    const float* __restrict__ fmT,     // (N,V,H,W,C) channel-last
    const float* __restrict__ sp,      // (N,P,5)
    const float* __restrict__ Rm,      // (N,V,3,3)
    const float* __restrict__ Tm,      // (N,V,3)
    const float* __restrict__ fv,      // (N,V,2)
    const float* __restrict__ cv,      // (N,V,2)
    const float* __restrict__ kv,      // (N,V,3)
    const float* __restrict__ pv,      // (N,V,2)
    const float* __restrict__ trans,   // (N,V,2,3)
    const float* __restrict__ wh,      // (N,V,2)
    const float* __restrict__ fmsz,    // (2,)
    float* __restrict__ out_feats,     // (N,P,V,C)
    float* __restrict__ out_bound,     // (N,P)
    float* __restrict__ out_sp)        // (N,P,5)
{
    const int pb = blockIdx.x;               // 0 .. N*(P/PTS)-1
    const int n  = pb >> 8;                  // P/PTS = 256
    const int p0 = (pb & 255) * PTS;
    const int t  = threadIdx.x;
    const int base_pt = n * P + p0;

    __shared__ int   s_idx[PTS * V][4];
    __shared__ float s_w[PTS * V][4];
    __shared__ float s_bnd[PTS * V];
    __shared__ int   s_nan[PTS];

    if (t < PTS) s_nan[t] = 0;
    if (t < PTS * 5) out_sp[base_pt * 5 + t] = sp[base_pt * 5 + t];

    if (t < PTS * V) {
        const int pt = t / V;
        const int v  = t - pt * V;
        const int nv = n * V + v;

        const float X = sp[(base_pt + pt) * 5 + 0];
        const float Y = sp[(base_pt + pt) * 5 + 1];
        const float Z = sp[(base_pt + pt) * 5 + 2];

        const float* Rv = Rm + nv * 9;
        const float tx = Tm[nv * 3 + 0], ty = Tm[nv * 3 + 1], tz = Tm[nv * 3 + 2];
        const float px = X - tx, py = Y - ty, pz = Z - tz;
        const float Xc0 = Rv[0] * px + Rv[1] * py + Rv[2] * pz;
        const float Xc1 = Rv[3] * px + Rv[4] * py + Rv[5] * pz;
        const float Xc2 = Rv[6] * px + Rv[7] * py + Rv[8] * pz;
        const float xn = Xc0 / Xc2;
        const float yn = Xc1 / Xc2;
        const float r2 = xn * xn + yn * yn;
        const float k1 = kv[nv * 3 + 0], k2 = kv[nv * 3 + 1], k3 = kv[nv * 3 + 2];
        const float p1 = pv[nv * 2 + 0], p2 = pv[nv * 2 + 1];
        const float radial = 1.0f + k1 * r2 + k2 * r2 * r2 + k3 * r2 * r2 * r2;
        const float xd = xn * radial + 2.0f * p1 * xn * yn + p2 * (r2 + 2.0f * xn * xn);
        const float yd = yn * radial + p1 * (r2 + 2.0f * yn * yn) + 2.0f * p2 * xn * yn;
        const float xy0 = xd * fv[nv * 2 + 0] + cv[nv * 2 + 0];
        const float xy1 = yd * fv[nv * 2 + 1] + cv[nv * 2 + 1];
        const float width  = wh[nv * 2 + 0];
        const float height = wh[nv * 2 + 1];
        const bool bound = (xy0 >= 0.0f) && (xy1 >= 0.0f) && (xy0 < width) && (xy1 < height);
        const float maxwh = fmaxf(width, height);
        const float pix0 = fminf(fmaxf(xy0, -1.0f), maxwh);
        const float pix1 = fminf(fmaxf(xy1, -1.0f), maxwh);
        const float* tr = trans + nv * 6;
        const float pt0 = tr[0] * pix0 + tr[1] * pix1 + tr[2];
        const float pt1 = tr[3] * pix0 + tr[4] * pix1 + tr[5];
        const float fm0 = fmsz[0], fm1 = fmsz[1];
        float g0 = pt0 / (fm0 - 1.0f) * 2.0f - 1.0f;
        float g1 = pt1 / (fm1 - 1.0f) * 2.0f - 1.0f;
        g0 = fminf(fmaxf(g0, -1.1f), 1.1f);
        g1 = fminf(fmaxf(g1, -1.1f), 1.1f);

        const float xg = (g0 + 1.0f) * 0.5f * (float)(W - 1);
        const float yg = (g1 + 1.0f) * 0.5f * (float)(H - 1);
        const float x0f = floorf(xg), y0f = floorf(yg);
        const float wx1 = xg - x0f, wx0 = 1.0f - wx1;
        const float wy1 = yg - y0f, wy0 = 1.0f - wy1;
        const int x0 = (int)x0f, y0 = (int)y0f;
        const int x1 = x0 + 1,  y1 = y0 + 1;
        const bool vx0 = (x0 >= 0) && (x0 <= W - 1);
        const bool vx1 = (x1 >= 0) && (x1 <= W - 1);
        const bool vy0 = (y0 >= 0) && (y0 <= H - 1);
        const bool vy1 = (y1 >= 0) && (y1 <= H - 1);
        const int x0c = min(max(x0, 0), W - 1);
        const int x1c = min(max(x1, 0), W - 1);
        const int y0c = min(max(y0, 0), H - 1);
        const int y1c = min(max(y1, 0), H - 1);

        s_idx[t][0] = y0c * W + x0c;
        s_idx[t][1] = y0c * W + x1c;
        s_idx[t][2] = y1c * W + x0c;
        s_idx[t][3] = y1c * W + x1c;
        s_w[t][0] = (vx0 && vy0) ? (wx0 * wy0) : 0.0f;
        s_w[t][1] = (vx1 && vy0) ? (wx1 * wy0) : 0.0f;
        s_w[t][2] = (vx0 && vy1) ? (wx0 * wy1) : 0.0f;
        s_w[t][3] = (vx1 && vy1) ? (wx1 * wy1) : 0.0f;
        s_bnd[t] = bound ? 1.0f : 0.0f;
    }
    __syncthreads();

    // Phase 2: streaming gather. Two 128-lane groups; 40 point-views each.
    {
        const int grp = t >> 7;          // 0..1
        const int c   = t & 127;         // channel
        const float* img_n = fmT + (size_t)(n * V) * HW * C;
        #pragma unroll 4
        for (int i = grp; i < PTS * V; i += 2) {
            const int pt = i / V;
            const int v  = i - pt * V;
            const float* img = img_n + (size_t)v * HW * C;
            const float f00 = img[(size_t)s_idx[i][0] * C + c];
            const float f10 = img[(size_t)s_idx[i][1] * C + c];
            const float f01 = img[(size_t)s_idx[i][2] * C + c];
            const float f11 = img[(size_t)s_idx[i][3] * C + c];
            const float s = f00 * s_w[i][0] + f10 * s_w[i][1]
                          + f01 * s_w[i][2] + f11 * s_w[i][3];
            const float feat = s * s_bnd[i];
            if (feat != feat) s_nan[pt] = 1;   // benign race
            __builtin_nontemporal_store(
                feat, &out_feats[((size_t)(base_pt + pt) * V + v) * C + c]);
        }
    }
    __syncthreads();

    if (t < PTS) {
        bool any_b = false;
        #pragma unroll
        for (int v = 0; v < V; ++v) any_b |= (s_bnd[t * V + v] != 0.0f);
        out_bound[base_pt + t] = (any_b && (s_nan[t] == 0)) ? 1.0f : 0.0f;
    }
}

extern "C" void kernel_launch(void* const* d_in, const int* in_sizes, int n_in,
                              void* d_out, int out_size, void* d_ws, size_t ws_size,
                              hipStream_t stream) {
    const float* fm    = (const float*)d_in[0];
    const float* sp    = (const float*)d_in[1];
    const float* Rm    = (const float*)d_in[2];
    const float* Tm    = (const float*)d_in[3];
    const float* fv    = (const float*)d_in[4];
    const float* cv    = (const float*)d_in[5];
    const float* kv    = (const float*)d_in[6];
    const float* pv    = (const float*)d_in[7];
    const float* trans = (const float*)d_in[8];
    const float* wh    = (const float*)d_in[9];
    const float* fmsz  = (const float*)d_in[10];

    float* out        = (float*)d_out;
    float* out_feats  = out;
    float* out_bound  = out + (size_t)N * P * V * C;
    float* out_sp     = out_bound + (size_t)N * P;

    float* fmT = (float*)d_ws;   // N*V*HW*C floats = 167.8 MB

    dim3 tgrid(HW / 64, N * V);
    transpose_kernel<<<tgrid, 256, 0, stream>>>(fm, fmT);

    project_sample_kernel<<<N * (P / PTS), 256, 0, stream>>>(
        fmT, sp, Rm, Tm, fv, cv, kv, pv, trans, wh, fmsz,
        out_feats, out_bound, out_sp);
}

// Round 5
// 287.696 us; speedup vs baseline: 1.5034x; 1.0477x over previous
//
#include <hip/hip_runtime.h>
#include <math.h>

#define N 4
#define V 5
#define C 128
#define H 128
#define W 128
#define P 4096
#define HW (H * W)
#define PTS 16              // points per project block

typedef float  fvec4 __attribute__((ext_vector_type(4)));
typedef unsigned short usvec4 __attribute__((ext_vector_type(4)));

__device__ __forceinline__ unsigned short f2bf_rne(float x) {
    unsigned u = __float_as_uint(x);
    unsigned rounding = 0x7fffu + ((u >> 16) & 1u);
    return (unsigned short)((u + rounding) >> 16);
}
__device__ __forceinline__ float bf2f(unsigned short b) {
    return __uint_as_float(((unsigned)b) << 16);
}

// ---------------------------------------------------------------------------
// Transpose (N,V,C,H,W) f32 -> (N,V,H,W,C) bf16.
// Tile: 64 hw x 128 c. 256 threads. LDS tile stays f32 (conflict-free),
// bf16 conversion at the store side (ushort4 = 8 B/lane).
// ---------------------------------------------------------------------------
__global__ __launch_bounds__(256) void transpose_kernel(
    const float* __restrict__ fm, unsigned short* __restrict__ fmT)
{
    const int nv  = blockIdx.y;          // 0..N*V-1
    const int hw0 = blockIdx.x * 64;     // tile start in hw
    __shared__ float lds[64][C + 1];     // +1 pad breaks power-of-2 stride

    const int t = threadIdx.x;

    // Load: thread covers 4 consecutive hw at one c; 16 c per pass, 8 passes.
    {
        const int hwl = (t & 15) * 4;
        const int cb  = t >> 4;          // 0..15
        const float* src = fm + (size_t)nv * C * HW + hw0 + hwl;
        for (int c = cb; c < C; c += 16) {
            const fvec4 v = __builtin_nontemporal_load(
                (const fvec4*)(src + (size_t)c * HW));
            lds[hwl + 0][c] = v.x;
            lds[hwl + 1][c] = v.y;
            lds[hwl + 2][c] = v.z;
            lds[hwl + 3][c] = v.w;
        }
    }
    __syncthreads();

    // Store: thread covers 4 consecutive c at one hw; 8 hw per pass, 8 passes.
    {
        const int c4 = (t & 31) * 4;
        unsigned short* dst = fmT + ((size_t)nv * HW + hw0) * C + c4;
        for (int hw = (t >> 5); hw < 64; hw += 8) {
            const fvec4 v = *(const fvec4*)&lds[hw][c4];
            usvec4 o;
            o.x = f2bf_rne(v.x);
            o.y = f2bf_rne(v.y);
            o.z = f2bf_rne(v.z);
            o.w = f2bf_rne(v.w);
            *(usvec4*)(dst + (size_t)hw * C) = o;
        }
    }
}

// ---------------------------------------------------------------------------
// Phase-split projection + gather from bf16 channel-last maps.
// Block = 256 threads, PTS points.
// Phase 1: 80 threads compute one (pt,view) projection each -> LDS.
// Phase 2: two 128-lane groups stream the coalesced channel gathers.
// ---------------------------------------------------------------------------
__global__ __launch_bounds__(256) void project_sample_kernel(
    const unsigned short* __restrict__ fmT, // (N,V,H,W,C) bf16
    const float* __restrict__ sp,      // (N,P,5)
    const float* __restrict__ Rm,      // (N,V,3,3)
    const float* __restrict__ Tm,      // (N,V,3)
    const float* __restrict__ fv,      // (N,V,2)
    const float* __restrict__ cv,      // (N,V,2)
    const float* __restrict__ kv,      // (N,V,3)
    const float* __restrict__ pv,      // (N,V,2)
    const float* __restrict__ trans,   // (N,V,2,3)
    const float* __restrict__ wh,      // (N,V,2)
    const float* __restrict__ fmsz,    // (2,)
    float* __restrict__ out_feats,     // (N,P,V,C)
    float* __restrict__ out_bound,     // (N,P)
    float* __restrict__ out_sp)        // (N,P,5)
{
    const int pb = blockIdx.x;               // 0 .. N*(P/PTS)-1
    const int n  = pb >> 8;                  // P/PTS = 256
    const int p0 = (pb & 255) * PTS;
    const int t  = threadIdx.x;
    const int base_pt = n * P + p0;

    __shared__ int   s_idx[PTS * V][4];
    __shared__ float s_w[PTS * V][4];
    __shared__ float s_bnd[PTS * V];
    __shared__ int   s_nan[PTS];

    if (t < PTS) s_nan[t] = 0;
    if (t < PTS * 5) out_sp[base_pt * 5 + t] = sp[base_pt * 5 + t];

    if (t < PTS * V) {
        const int pt = t / V;
        const int v  = t - pt * V;
        const int nv = n * V + v;

        const float X = sp[(base_pt + pt) * 5 + 0];
        const float Y = sp[(base_pt + pt) * 5 + 1];
        const float Z = sp[(base_pt + pt) * 5 + 2];

        const float* Rv = Rm + nv * 9;
        const float tx = Tm[nv * 3 + 0], ty = Tm[nv * 3 + 1], tz = Tm[nv * 3 + 2];
        const float px = X - tx, py = Y - ty, pz = Z - tz;
        const float Xc0 = Rv[0] * px + Rv[1] * py + Rv[2] * pz;
        const float Xc1 = Rv[3] * px + Rv[4] * py + Rv[5] * pz;
        const float Xc2 = Rv[6] * px + Rv[7] * py + Rv[8] * pz;
        const float xn = Xc0 / Xc2;
        const float yn = Xc1 / Xc2;
        const float r2 = xn * xn + yn * yn;
        const float k1 = kv[nv * 3 + 0], k2 = kv[nv * 3 + 1], k3 = kv[nv * 3 + 2];
        const float p1 = pv[nv * 2 + 0], p2 = pv[nv * 2 + 1];
        const float radial = 1.0f + k1 * r2 + k2 * r2 * r2 + k3 * r2 * r2 * r2;
        const float xd = xn * radial + 2.0f * p1 * xn * yn + p2 * (r2 + 2.0f * xn * xn);
        const float yd = yn * radial + p1 * (r2 + 2.0f * yn * yn) + 2.0f * p2 * xn * yn;
        const float xy0 = xd * fv[nv * 2 + 0] + cv[nv * 2 + 0];
        const float xy1 = yd * fv[nv * 2 + 1] + cv[nv * 2 + 1];
        const float width  = wh[nv * 2 + 0];
        const float height = wh[nv * 2 + 1];
        const bool bound = (xy0 >= 0.0f) && (xy1 >= 0.0f) && (xy0 < width) && (xy1 < height);
        const float maxwh = fmaxf(width, height);
        const float pix0 = fminf(fmaxf(xy0, -1.0f), maxwh);
        const float pix1 = fminf(fmaxf(xy1, -1.0f), maxwh);
        const float* tr = trans + nv * 6;
        const float pt0 = tr[0] * pix0 + tr[1] * pix1 + tr[2];
        const float pt1 = tr[3] * pix0 + tr[4] * pix1 + tr[5];
        const float fm0 = fmsz[0], fm1 = fmsz[1];
        float g0 = pt0 / (fm0 - 1.0f) * 2.0f - 1.0f;
        float g1 = pt1 / (fm1 - 1.0f) * 2.0f - 1.0f;
        g0 = fminf(fmaxf(g0, -1.1f), 1.1f);
        g1 = fminf(fmaxf(g1, -1.1f), 1.1f);

        const float xg = (g0 + 1.0f) * 0.5f * (float)(W - 1);
        const float yg = (g1 + 1.0f) * 0.5f * (float)(H - 1);
        const float x0f = floorf(xg), y0f = floorf(yg);
        const float wx1 = xg - x0f, wx0 = 1.0f - wx1;
        const float wy1 = yg - y0f, wy0 = 1.0f - wy1;
        const int x0 = (int)x0f, y0 = (int)y0f;
        const int x1 = x0 + 1,  y1 = y0 + 1;
        const bool vx0 = (x0 >= 0) && (x0 <= W - 1);
        const bool vx1 = (x1 >= 0) && (x1 <= W - 1);
        const bool vy0 = (y0 >= 0) && (y0 <= H - 1);
        const bool vy1 = (y1 >= 0) && (y1 <= H - 1);
        const int x0c = min(max(x0, 0), W - 1);
        const int x1c = min(max(x1, 0), W - 1);
        const int y0c = min(max(y0, 0), H - 1);
        const int y1c = min(max(y1, 0), H - 1);

        s_idx[t][0] = y0c * W + x0c;
        s_idx[t][1] = y0c * W + x1c;
        s_idx[t][2] = y1c * W + x0c;
        s_idx[t][3] = y1c * W + x1c;
        s_w[t][0] = (vx0 && vy0) ? (wx0 * wy0) : 0.0f;
        s_w[t][1] = (vx1 && vy0) ? (wx1 * wy0) : 0.0f;
        s_w[t][2] = (vx0 && vy1) ? (wx0 * wy1) : 0.0f;
        s_w[t][3] = (vx1 && vy1) ? (wx1 * wy1) : 0.0f;
        s_bnd[t] = bound ? 1.0f : 0.0f;
    }
    __syncthreads();

    // Phase 2: streaming gather. Two 128-lane groups; 40 point-views each.
    {
        const int grp = t >> 7;          // 0..1
        const int c   = t & 127;         // channel
        const unsigned short* img_n = fmT + (size_t)(n * V) * HW * C;
        #pragma unroll 4
        for (int i = grp; i < PTS * V; i += 2) {
            const int pt = i / V;
            const int v  = i - pt * V;
            const unsigned short* img = img_n + (size_t)v * HW * C;
            const float f00 = bf2f(img[(size_t)s_idx[i][0] * C + c]);
            const float f10 = bf2f(img[(size_t)s_idx[i][1] * C + c]);
            const float f01 = bf2f(img[(size_t)s_idx[i][2] * C + c]);
            const float f11 = bf2f(img[(size_t)s_idx[i][3] * C + c]);
            const float s = f00 * s_w[i][0] + f10 * s_w[i][1]
                          + f01 * s_w[i][2] + f11 * s_w[i][3];
            const float feat = s * s_bnd[i];
            if (feat != feat) s_nan[pt] = 1;   // benign race
            __builtin_nontemporal_store(
                feat, &out_feats[((size_t)(base_pt + pt) * V + v) * C + c]);
        }
    }
    __syncthreads();

    if (t < PTS) {
        bool any_b = false;
        #pragma unroll
        for (int v = 0; v < V; ++v) any_b |= (s_bnd[t * V + v] != 0.0f);
        out_bound[base_pt + t] = (any_b && (s_nan[t] == 0)) ? 1.0f : 0.0f;
    }
}

extern "C" void kernel_launch(void* const* d_in, const int* in_sizes, int n_in,
                              void* d_out, int out_size, void* d_ws, size_t ws_size,
                              hipStream_t stream) {
    const float* fm    = (const float*)d_in[0];
    const float* sp    = (const float*)d_in[1];
    const float* Rm    = (const float*)d_in[2];
    const float* Tm    = (const float*)d_in[3];
    const float* fv    = (const float*)d_in[4];
    const float* cv    = (const float*)d_in[5];
    const float* kv    = (const float*)d_in[6];
    const float* pv    = (const float*)d_in[7];
    const float* trans = (const float*)d_in[8];
    const float* wh    = (const float*)d_in[9];
    const float* fmsz  = (const float*)d_in[10];

    float* out        = (float*)d_out;
    float* out_feats  = out;
    float* out_bound  = out + (size_t)N * P * V * C;
    float* out_sp     = out_bound + (size_t)N * P;

    unsigned short* fmT = (unsigned short*)d_ws;  // N*V*HW*C bf16 = 83.9 MB

    dim3 tgrid(HW / 64, N * V);
    transpose_kernel<<<tgrid, 256, 0, stream>>>(fm, fmT);

    project_sample_kernel<<<N * (P / PTS), 256, 0, stream>>>(
        fmT, sp, Rm, Tm, fv, cv, kv, pv, trans, wh, fmsz,
        out_feats, out_bound, out_sp);
}

// Round 6
// 287.152 us; speedup vs baseline: 1.5063x; 1.0019x over previous
//
#include <hip/hip_runtime.h>
#include <math.h>

#define N 4
#define V 5
#define C 128
#define H 128
#define W 128
#define P 4096
#define HW (H * W)
#define PTS 16              // points per project block

typedef float  fvec4 __attribute__((ext_vector_type(4)));
typedef unsigned short usvec4 __attribute__((ext_vector_type(4)));

__device__ __forceinline__ unsigned short f2bf_rne(float x) {
    unsigned u = __float_as_uint(x);
    unsigned rounding = 0x7fffu + ((u >> 16) & 1u);
    return (unsigned short)((u + rounding) >> 16);
}
__device__ __forceinline__ float bf2f(unsigned short b) {
    return __uint_as_float(((unsigned)b) << 16);
}

// ---------------------------------------------------------------------------
// Transpose (N,V,C,H,W) f32 -> (N,V,H,W,C) bf16.
// Tile: 64 hw x 128 c. 256 threads. LDS tile stays f32 (conflict-free),
// bf16 conversion at the store side (ushort4 = 8 B/lane).
// ---------------------------------------------------------------------------
__global__ __launch_bounds__(256) void transpose_kernel(
    const float* __restrict__ fm, unsigned short* __restrict__ fmT)
{
    const int nv  = blockIdx.y;          // 0..N*V-1
    const int hw0 = blockIdx.x * 64;     // tile start in hw
    __shared__ float lds[64][C + 1];     // +1 pad breaks power-of-2 stride

    const int t = threadIdx.x;

    // Load: thread covers 4 consecutive hw at one c; 16 c per pass, 8 passes.
    {
        const int hwl = (t & 15) * 4;
        const int cb  = t >> 4;          // 0..15
        const float* src = fm + (size_t)nv * C * HW + hw0 + hwl;
        for (int c = cb; c < C; c += 16) {
            const fvec4 v = __builtin_nontemporal_load(
                (const fvec4*)(src + (size_t)c * HW));
            lds[hwl + 0][c] = v.x;
            lds[hwl + 1][c] = v.y;
            lds[hwl + 2][c] = v.z;
            lds[hwl + 3][c] = v.w;
        }
    }
    __syncthreads();

    // Store: thread covers 4 consecutive c at one hw; 8 hw per pass, 8 passes.
    {
        const int c4 = (t & 31) * 4;
        unsigned short* dst = fmT + ((size_t)nv * HW + hw0) * C + c4;
        for (int hw = (t >> 5); hw < 64; hw += 8) {
            const fvec4 v = *(const fvec4*)&lds[hw][c4];
            usvec4 o;
            o.x = f2bf_rne(v.x);
            o.y = f2bf_rne(v.y);
            o.z = f2bf_rne(v.z);
            o.w = f2bf_rne(v.w);
            *(usvec4*)(dst + (size_t)hw * C) = o;
        }
    }
}

// ---------------------------------------------------------------------------
// Phase-split projection + gather from bf16 channel-last maps.
// Block = 256 threads, PTS points.
// Phase 1: 80 threads compute one (pt,view) projection each -> LDS.
// Phase 2: 32 threads per point-view, 4 channels/thread (ushort4 corner
// loads, float4 stores); 8 point-views in flight, 10 iterations.
// ---------------------------------------------------------------------------
__global__ __launch_bounds__(256) void project_sample_kernel(
    const unsigned short* __restrict__ fmT, // (N,V,H,W,C) bf16
    const float* __restrict__ sp,      // (N,P,5)
    const float* __restrict__ Rm,      // (N,V,3,3)
    const float* __restrict__ Tm,      // (N,V,3)
    const float* __restrict__ fv,      // (N,V,2)
    const float* __restrict__ cv,      // (N,V,2)
    const float* __restrict__ kv,      // (N,V,3)
    const float* __restrict__ pv,      // (N,V,2)
    const float* __restrict__ trans,   // (N,V,2,3)
    const float* __restrict__ wh,      // (N,V,2)
    const float* __restrict__ fmsz,    // (2,)
    float* __restrict__ out_feats,     // (N,P,V,C)
    float* __restrict__ out_bound,     // (N,P)
    float* __restrict__ out_sp)        // (N,P,5)
{
    const int pb = blockIdx.x;               // 0 .. N*(P/PTS)-1
    const int n  = pb >> 8;                  // P/PTS = 256
    const int p0 = (pb & 255) * PTS;
    const int t  = threadIdx.x;
    const int base_pt = n * P + p0;

    __shared__ int   s_idx[PTS * V][4];
    __shared__ float s_w[PTS * V][4];
    __shared__ float s_bnd[PTS * V];
    __shared__ int   s_nan[PTS];

    if (t < PTS) s_nan[t] = 0;
    if (t < PTS * 5) out_sp[base_pt * 5 + t] = sp[base_pt * 5 + t];

    if (t < PTS * V) {
        const int pt = t / V;
        const int v  = t - pt * V;
        const int nv = n * V + v;

        const float X = sp[(base_pt + pt) * 5 + 0];
        const float Y = sp[(base_pt + pt) * 5 + 1];
        const float Z = sp[(base_pt + pt) * 5 + 2];

        const float* Rv = Rm + nv * 9;
        const float tx = Tm[nv * 3 + 0], ty = Tm[nv * 3 + 1], tz = Tm[nv * 3 + 2];
        const float px = X - tx, py = Y - ty, pz = Z - tz;
        const float Xc0 = Rv[0] * px + Rv[1] * py + Rv[2] * pz;
        const float Xc1 = Rv[3] * px + Rv[4] * py + Rv[5] * pz;
        const float Xc2 = Rv[6] * px + Rv[7] * py + Rv[8] * pz;
        const float xn = Xc0 / Xc2;
        const float yn = Xc1 / Xc2;
        const float r2 = xn * xn + yn * yn;
        const float k1 = kv[nv * 3 + 0], k2 = kv[nv * 3 + 1], k3 = kv[nv * 3 + 2];
        const float p1 = pv[nv * 2 + 0], p2 = pv[nv * 2 + 1];
        const float radial = 1.0f + k1 * r2 + k2 * r2 * r2 + k3 * r2 * r2 * r2;
        const float xd = xn * radial + 2.0f * p1 * xn * yn + p2 * (r2 + 2.0f * xn * xn);
        const float yd = yn * radial + p1 * (r2 + 2.0f * yn * yn) + 2.0f * p2 * xn * yn;
        const float xy0 = xd * fv[nv * 2 + 0] + cv[nv * 2 + 0];
        const float xy1 = yd * fv[nv * 2 + 1] + cv[nv * 2 + 1];
        const float width  = wh[nv * 2 + 0];
        const float height = wh[nv * 2 + 1];
        const bool bound = (xy0 >= 0.0f) && (xy1 >= 0.0f) && (xy0 < width) && (xy1 < height);
        const float maxwh = fmaxf(width, height);
        const float pix0 = fminf(fmaxf(xy0, -1.0f), maxwh);
        const float pix1 = fminf(fmaxf(xy1, -1.0f), maxwh);
        const float* tr = trans + nv * 6;
        const float pt0 = tr[0] * pix0 + tr[1] * pix1 + tr[2];
        const float pt1 = tr[3] * pix0 + tr[4] * pix1 + tr[5];
        const float fm0 = fmsz[0], fm1 = fmsz[1];
        float g0 = pt0 / (fm0 - 1.0f) * 2.0f - 1.0f;
        float g1 = pt1 / (fm1 - 1.0f) * 2.0f - 1.0f;
        g0 = fminf(fmaxf(g0, -1.1f), 1.1f);
        g1 = fminf(fmaxf(g1, -1.1f), 1.1f);

        const float xg = (g0 + 1.0f) * 0.5f * (float)(W - 1);
        const float yg = (g1 + 1.0f) * 0.5f * (float)(H - 1);
        const float x0f = floorf(xg), y0f = floorf(yg);
        const float wx1 = xg - x0f, wx0 = 1.0f - wx1;
        const float wy1 = yg - y0f, wy0 = 1.0f - wy1;
        const int x0 = (int)x0f, y0 = (int)y0f;
        const int x1 = x0 + 1,  y1 = y0 + 1;
        const bool vx0 = (x0 >= 0) && (x0 <= W - 1);
        const bool vx1 = (x1 >= 0) && (x1 <= W - 1);
        const bool vy0 = (y0 >= 0) && (y0 <= H - 1);
        const bool vy1 = (y1 >= 0) && (y1 <= H - 1);
        const int x0c = min(max(x0, 0), W - 1);
        const int x1c = min(max(x1, 0), W - 1);
        const int y0c = min(max(y0, 0), H - 1);
        const int y1c = min(max(y1, 0), H - 1);

        s_idx[t][0] = y0c * W + x0c;
        s_idx[t][1] = y0c * W + x1c;
        s_idx[t][2] = y1c * W + x0c;
        s_idx[t][3] = y1c * W + x1c;
        s_w[t][0] = (vx0 && vy0) ? (wx0 * wy0) : 0.0f;
        s_w[t][1] = (vx1 && vy0) ? (wx1 * wy0) : 0.0f;
        s_w[t][2] = (vx0 && vy1) ? (wx0 * wy1) : 0.0f;
        s_w[t][3] = (vx1 && vy1) ? (wx1 * wy1) : 0.0f;
        s_bnd[t] = bound ? 1.0f : 0.0f;
    }
    __syncthreads();

    // Phase 2: 32 threads per point-view, 4 channels each.
    {
        const int grp = t >> 5;          // 0..7 point-view group
        const int c4  = (t & 31) * 4;    // channel base
        const unsigned short* img_n = fmT + (size_t)(n * V) * HW * C;
        #pragma unroll 2
        for (int i = grp; i < PTS * V; i += 8) {
            const int pt = i / V;
            const int v  = i - pt * V;
            const unsigned short* img = img_n + (size_t)v * HW * C + c4;
            const usvec4 b00 = *(const usvec4*)(img + (size_t)s_idx[i][0] * C);
            const usvec4 b10 = *(const usvec4*)(img + (size_t)s_idx[i][1] * C);
            const usvec4 b01 = *(const usvec4*)(img + (size_t)s_idx[i][2] * C);
            const usvec4 b11 = *(const usvec4*)(img + (size_t)s_idx[i][3] * C);
            const float w00 = s_w[i][0], w10 = s_w[i][1];
            const float w01 = s_w[i][2], w11 = s_w[i][3];
            const float bnd = s_bnd[i];
            fvec4 f;
            f.x = (bf2f(b00.x) * w00 + bf2f(b10.x) * w10
                 + bf2f(b01.x) * w01 + bf2f(b11.x) * w11) * bnd;
            f.y = (bf2f(b00.y) * w00 + bf2f(b10.y) * w10
                 + bf2f(b01.y) * w01 + bf2f(b11.y) * w11) * bnd;
            f.z = (bf2f(b00.z) * w00 + bf2f(b10.z) * w10
                 + bf2f(b01.z) * w01 + bf2f(b11.z) * w11) * bnd;
            f.w = (bf2f(b00.w) * w00 + bf2f(b10.w) * w10
                 + bf2f(b01.w) * w01 + bf2f(b11.w) * w11) * bnd;
            if ((f.x != f.x) | (f.y != f.y) | (f.z != f.z) | (f.w != f.w))
                s_nan[pt] = 1;           // benign race
            __builtin_nontemporal_store(
                f, (fvec4*)&out_feats[((size_t)(base_pt + pt) * V + v) * C + c4]);
        }
    }
    __syncthreads();

    if (t < PTS) {
        bool any_b = false;
        #pragma unroll
        for (int v = 0; v < V; ++v) any_b |= (s_bnd[t * V + v] != 0.0f);
        out_bound[base_pt + t] = (any_b && (s_nan[t] == 0)) ? 1.0f : 0.0f;
    }
}

extern "C" void kernel_launch(void* const* d_in, const int* in_sizes, int n_in,
                              void* d_out, int out_size, void* d_ws, size_t ws_size,
                              hipStream_t stream) {
    const float* fm    = (const float*)d_in[0];
    const float* sp    = (const float*)d_in[1];
    const float* Rm    = (const float*)d_in[2];
    const float* Tm    = (const float*)d_in[3];
    const float* fv    = (const float*)d_in[4];
    const float* cv    = (const float*)d_in[5];
    const float* kv    = (const float*)d_in[6];
    const float* pv    = (const float*)d_in[7];
    const float* trans = (const float*)d_in[8];
    const float* wh    = (const float*)d_in[9];
    const float* fmsz  = (const float*)d_in[10];

    float* out        = (float*)d_out;
    float* out_feats  = out;
    float* out_bound  = out + (size_t)N * P * V * C;
    float* out_sp     = out_bound + (size_t)N * P;

    unsigned short* fmT = (unsigned short*)d_ws;  // N*V*HW*C bf16 = 83.9 MB

    dim3 tgrid(HW / 64, N * V);
    transpose_kernel<<<tgrid, 256, 0, stream>>>(fm, fmT);

    project_sample_kernel<<<N * (P / PTS), 256, 0, stream>>>(
        fmT, sp, Rm, Tm, fv, cv, kv, pv, trans, wh, fmsz,
        out_feats, out_bound, out_sp);
}